// Round 2
// baseline (526.890 us; speedup 1.0000x reference)
//
#include <hip/hip_runtime.h>

// MaxPool2d k=2 s=2 on (32, 64, 224, 224) fp32 -> (32, 64, 112, 112).
// Purely memory-bound: 411 MB read (once) + 103 MB write = 514 MB ideal traffic.
// Roofline at ~6.3 TB/s achievable HBM: ~82 us.
//
// Geometry is HARD-CODED (problem shape is fixed) so the grid cannot be
// perturbed by out_size unit ambiguity (bytes vs elements). Grid-stride loop
// makes the kernel correct and OOB-safe under ANY grid size (defensive: an
// oversized grid must not fault the container).
//
// Each thread-iteration: 4x 16B input loads (an 8-wide x 2-high patch = four
// 2x2 windows), one 16B store. All accesses coalesced, non-temporal (data is
// streamed exactly once and exceeds the 256 MB L3).

#define N_PLANES 2048                 // 32 * 64
#define H_IN 224
#define W_IN 224
#define H_OUT 112
#define W_OUT 112
#define IN_ROW_F4 (W_IN / 4)          // 56 float4 per input row
#define PLANE_IN_F4 (H_IN * W_IN / 4) // 12544 float4 per input plane
#define OUT_ROW_F4 (W_OUT / 4)        // 28 float4 per output row
#define PLANE_OUT_F4 (H_OUT * W_OUT / 4) // 3136 float4 per output plane
#define TOTAL_OUT_F4 (N_PLANES * PLANE_OUT_F4) // 6,422,528
#define BLOCK 256
#define GRID (TOTAL_OUT_F4 / BLOCK)   // 25088 exactly, no tail

typedef float f4 __attribute__((ext_vector_type(4)));

__global__ __launch_bounds__(BLOCK) void maxpool2d_kernel(
    const f4* __restrict__ in4, f4* __restrict__ out4) {
    const int stride = gridDim.x * BLOCK;
    for (int t = blockIdx.x * BLOCK + threadIdx.x; t < TOTAL_OUT_F4; t += stride) {
        // t = plane * PLANE_OUT_F4 + row * OUT_ROW_F4 + col4 (linear out index)
        int col4  = t % OUT_ROW_F4;       // float4 index within output row
        int tmp   = t / OUT_ROW_F4;
        int row   = tmp % H_OUT;          // output row
        int plane = tmp / H_OUT;          // n*C + c

        // Input: rows 2*row and 2*row+1, starting float4 = col4*2
        int base = plane * PLANE_IN_F4 + (2 * row) * IN_ROW_F4 + col4 * 2;
        f4 a0 = __builtin_nontemporal_load(&in4[base]);
        f4 a1 = __builtin_nontemporal_load(&in4[base + 1]);
        f4 b0 = __builtin_nontemporal_load(&in4[base + IN_ROW_F4]);
        f4 b1 = __builtin_nontemporal_load(&in4[base + IN_ROW_F4 + 1]);

        f4 r;
        r[0] = fmaxf(fmaxf(a0[0], a0[1]), fmaxf(b0[0], b0[1]));
        r[1] = fmaxf(fmaxf(a0[2], a0[3]), fmaxf(b0[2], b0[3]));
        r[2] = fmaxf(fmaxf(a1[0], a1[1]), fmaxf(b1[0], b1[1]));
        r[3] = fmaxf(fmaxf(a1[2], a1[3]), fmaxf(b1[2], b1[3]));

        __builtin_nontemporal_store(r, &out4[t]);
    }
}

extern "C" void kernel_launch(void* const* d_in, const int* in_sizes, int n_in,
                              void* d_out, int out_size, void* d_ws, size_t ws_size,
                              hipStream_t stream) {
    const f4* in4 = (const f4*)d_in[0];
    f4* out4 = (f4*)d_out;
    maxpool2d_kernel<<<GRID, BLOCK, 0, stream>>>(in4, out4);
}